// Round 1
// baseline (171.820 us; speedup 1.0000x reference)
//
#include <hip/hip_runtime.h>

#define BB 16
#define NN 1024
#define CC 64

typedef __attribute__((ext_vector_type(8))) short short8;
typedef __attribute__((ext_vector_type(4))) float f32x4;
typedef __attribute__((ext_vector_type(4))) int   i32x4;

typedef __attribute__((address_space(3))) void lds_void_t;
typedef const __attribute__((address_space(1))) void gbl_void_t;

__device__ __forceinline__ void load_lds16(const void* g, void* l) {
    __builtin_amdgcn_global_load_lds((gbl_void_t*)g, (lds_void_t*)l, 16, 0, 0);
}

__device__ __forceinline__ unsigned short bf16_rne(float f) {
    unsigned u = __float_as_uint(f);
    u += 0x7fffu + ((u >> 16) & 1u);
    return (unsigned short)(u >> 16);
}

// ---------------- Kernel 1: xw = x@W_rel -> bf16 swizzled (B-frag order);
//                  out = x@W_root + b_rel (fp32) ----------------
extern "C" __global__ __launch_bounds__(256)
void precompute(const float* __restrict__ x, const float* __restrict__ W_rel,
                const float* __restrict__ W_root, const float* __restrict__ b_rel,
                unsigned short* __restrict__ xw_sw, float* __restrict__ out)
{
    __shared__ float wrel_s[64 * 64];
    __shared__ float wroot_s[64 * 64];
    __shared__ float x_s[16 * 68];

    const int t = threadIdx.x;
    #pragma unroll
    for (int k = 0; k < 4; ++k) {
        int i4 = t + 256 * k;
        ((float4*)wrel_s)[i4]  = ((const float4*)W_rel)[i4];
        ((float4*)wroot_s)[i4] = ((const float4*)W_root)[i4];
    }
    const int row0 = blockIdx.x * 16;
    {
        int r = t >> 4, c4 = t & 15;
        *(float4*)(x_s + r * 68 + c4 * 4) = ((const float4*)(x + (size_t)(row0 + r) * CC))[c4];
    }
    __syncthreads();

    const int c4 = t & 15;
    const int r  = t >> 4;
    float aw0 = 0.f, aw1 = 0.f, aw2 = 0.f, aw3 = 0.f;
    float ar0 = 0.f, ar1 = 0.f, ar2 = 0.f, ar3 = 0.f;
    const float* xrow = x_s + r * 68;
    #pragma unroll 8
    for (int k = 0; k < 64; ++k) {
        float xv = xrow[k];
        float4 wv = ((const float4*)(wrel_s  + k * 64))[c4];
        float4 rv = ((const float4*)(wroot_s + k * 64))[c4];
        aw0 += xv * wv.x; aw1 += xv * wv.y; aw2 += xv * wv.z; aw3 += xv * wv.w;
        ar0 += xv * rv.x; ar1 += xv * rv.y; ar2 += xv * rv.z; ar3 += xv * rv.w;
    }

    const int row_g = row0 + r;
    {
        const float4 bv = ((const float4*)b_rel)[c4];
        ((float4*)out)[(size_t)row_g * 16 + c4] =
            make_float4(ar0 + bv.x, ar1 + bv.y, ar2 + bv.z, ar3 + bv.w);
    }
    {
        const int b = row_g >> 10;
        const int k = row_g & 1023;
        const int kb = k >> 5;
        const int qk = (k >> 3) & 3;
        const int j  = k & 7;
        const int c  = 4 * c4;
        const int n0 = c >> 4;
        const int n  = c & 15;
        size_t off = ((size_t)b << 16) + (size_t)((kb * 4 + n0) << 9)
                   + (size_t)((n + (qk << 4)) << 3) + j;
        xw_sw[off]      = bf16_rne(aw0);
        xw_sw[off + 8]  = bf16_rne(aw1);
        xw_sw[off + 16] = bf16_rne(aw2);
        xw_sw[off + 24] = bf16_rne(aw3);
    }
}

// ---------------- Kernel 2: out += (adj .* w_edge[ea]) @ xw  (bf16 MFMA) ----
// v2: latency-bound fix. 32-wide K chunks, software-pipelined:
//   - 3-buffer LDS rotation (3 x 8KB {adj 4KB, ea 4KB} = 24KB)
//   - ONE raw s_barrier per chunk + counted `s_waitcnt vmcnt(4)` (never 0 in
//     the loop) -> next chunk's adj/ea DMA + bf-reg loads stay in flight
//     across the barrier (T3/T4 minimum pattern)
//   - xw B-frags loaded straight to VGPRs (coalesced 1KB/wave, L2-resident),
//     double-buffered in regs; no LDS staging for them
//   - wave (wm,wn) owns a disjoint 16x32 output tile -> no cross-wave
//     reduction pass; direct atomicAdd
// grid = B * (N/32) * 2 = 1024 blocks x 256 threads; 24KB LDS -> 4 blk/CU,
// entire grid co-resident (zero tail round).
extern "C" __global__ __launch_bounds__(256, 4)
void gnn_mfma(const float* __restrict__ adj, const int* __restrict__ ea,
              const float* __restrict__ w_edge,
              const unsigned short* __restrict__ xw_sw,
              float* __restrict__ out)
{
    __shared__ __align__(16) char lds[24576];

    const int t    = threadIdx.x;
    const int w    = t >> 6;
    const int lane = t & 63;
    const int m    = lane & 15;
    const int q    = lane >> 4;
    const int wm   = w >> 1;           // row half (also stage frag mh)
    const int wn   = w & 1;            // col half (also stage k-half h)

    const int mtile = blockIdx.x & 31;
    const int kh    = (blockIdx.x >> 5) & 1;
    const int b     = blockIdx.x >> 6;
    const int row0  = mtile << 5;

    // cubic through (e, w_edge[e]) for e=0..3 — exact branchless gather
    const float w0 = w_edge[0], w1 = w_edge[1], w2 = w_edge[2], w3 = w_edge[3];
    const float d1 = w1 - w0;
    const float d2 = w2 - 2.f * w1 + w0;
    const float d3 = w3 - 3.f * w2 + 3.f * w1 - w0;
    const float c3 = d3 * (1.f / 6.f);
    const float c2 = 0.5f * d2 - 0.5f * d3;
    const float c1 = d1 - 0.5f * d2 + (1.f / 3.f) * d3;
    const float c0 = w0;

    // ---- stage addressing: wave w loads adj/ea unit (mh=wm, h=wn) ----
    const size_t bbase = ((size_t)b << 20);                 // b * N * N
    const int row_s = row0 + (wm << 4) + m;
    const int kbase = (kh << 9) + (q << 3) + (wn << 2);
    const float* adjp = adj + bbase + ((size_t)row_s << 10) + kbase;
    const int*   eap  = ea  + bbase + ((size_t)row_s << 10) + kbase;
    const int dA = (wm << 11) + (wn << 10);                 // wave-uniform LDS off

    // ---- bf (xw B-frag) addressing: chunk c, frags n0 = wn*2, wn*2+1 ----
    const unsigned short* xwp = xw_sw + ((size_t)b << 16)
                              + ((size_t)(((kh << 4) << 2) + (wn << 1)) << 9)
                              + ((size_t)lane << 3);

    f32x4 acc0 = {0.f, 0.f, 0.f, 0.f};
    f32x4 acc1 = acc0;
    short8 bfr[2][2];

#define WSEL(ev) __builtin_fmaf(__builtin_fmaf(__builtin_fmaf(c3, (float)(ev), c2), (float)(ev), c1), (float)(ev), c0)
#define BUFP(i) (lds + 8192 * (i))
#define STAGE(c, bi) do { \
        load_lds16(adjp + ((c) << 5), BUFP(bi) + dA); \
        load_lds16(eap  + ((c) << 5), BUFP(bi) + 4096 + dA); \
    } while (0)
#define LDBF(c, r) do { \
        bfr[r][0] = *(const short8*)(xwp + ((size_t)(c) << 11)); \
        bfr[r][1] = *(const short8*)(xwp + ((size_t)(c) << 11) + 512); \
    } while (0)
#define COMPUTE(bi, r) do { \
        const char* fb = BUFP(bi) + (wm << 11) + (lane << 4); \
        f32x4 alo = *(const f32x4*)(fb); \
        f32x4 ahi = *(const f32x4*)(fb + 1024); \
        i32x4 elo = *(const i32x4*)(fb + 4096); \
        i32x4 ehi = *(const i32x4*)(fb + 5120); \
        float p0 = alo[0] * WSEL(elo[0]); \
        float p1 = alo[1] * WSEL(elo[1]); \
        float p2 = alo[2] * WSEL(elo[2]); \
        float p3 = alo[3] * WSEL(elo[3]); \
        float p4 = ahi[0] * WSEL(ehi[0]); \
        float p5 = ahi[1] * WSEL(ehi[1]); \
        float p6 = ahi[2] * WSEL(ehi[2]); \
        float p7 = ahi[3] * WSEL(ehi[3]); \
        union { int i[4]; short8 s8; } af; \
        af.i[0] = __builtin_amdgcn_perm(__float_as_uint(p1), __float_as_uint(p0), 0x07060302u); \
        af.i[1] = __builtin_amdgcn_perm(__float_as_uint(p3), __float_as_uint(p2), 0x07060302u); \
        af.i[2] = __builtin_amdgcn_perm(__float_as_uint(p5), __float_as_uint(p4), 0x07060302u); \
        af.i[3] = __builtin_amdgcn_perm(__float_as_uint(p7), __float_as_uint(p6), 0x07060302u); \
        acc0 = __builtin_amdgcn_mfma_f32_16x16x32_bf16(af.s8, bfr[r][0], acc0, 0, 0, 0); \
        acc1 = __builtin_amdgcn_mfma_f32_16x16x32_bf16(af.s8, bfr[r][1], acc1, 0, 0, 0); \
    } while (0)

    // prologue: chunk 0 in flight
    STAGE(0, 0);
    LDBF(0, 0);

    // 16 chunks of 32 k; one barrier per chunk; vmcnt counted, never 0 mid-loop.
    // Per iteration this wave issues 4 VMEM ops (2 DMA + 2 bf loads) for c+1;
    // vmcnt(4) waits exactly until chunk c's 4 ops have landed.
    #pragma unroll 16
    for (int c = 0; c < 16; ++c) {
        if (c < 15) {
            STAGE(c + 1, (c + 1) % 3);
            LDBF(c + 1, (c + 1) & 1);
            asm volatile("s_waitcnt vmcnt(4)" ::: "memory");
        } else {
            asm volatile("s_waitcnt vmcnt(0)" ::: "memory");
        }
        __builtin_amdgcn_s_barrier();
        COMPUTE(c % 3, c & 1);
    }

#undef COMPUTE
#undef LDBF
#undef STAGE
#undef BUFP
#undef WSEL

    // ---- epilogue: wave owns rows [row0+wm*16, +16) x cols [wn*32, +32) ----
    float* ob = out + ((((size_t)b << 10) + row0 + (wm << 4) + (q << 2)) << 6)
              + (wn << 5) + m;
    #pragma unroll
    for (int rg = 0; rg < 4; ++rg) {
        atomicAdd(ob + rg * 64,      acc0[rg]);
        atomicAdd(ob + rg * 64 + 16, acc1[rg]);
    }
}

extern "C" void kernel_launch(void* const* d_in, const int* in_sizes, int n_in,
                              void* d_out, int out_size, void* d_ws, size_t ws_size,
                              hipStream_t stream) {
    const float* x      = (const float*)d_in[0];
    const float* adj    = (const float*)d_in[1];
    const int*   ea     = (const int*)  d_in[2];
    const float* W_rel  = (const float*)d_in[3];
    const float* b_rel  = (const float*)d_in[4];
    const float* W_root = (const float*)d_in[5];
    const float* w_edge = (const float*)d_in[6];
    float* out = (float*)d_out;

    unsigned short* xw_sw = (unsigned short*)d_ws;   // B*N*C bf16 = 2 MiB

    precompute<<<BB * NN / 16, 256, 0, stream>>>(x, W_rel, W_root, b_rel, xw_sw, out);
    gnn_mfma<<<BB * (NN / 32) * 2, 256, 0, stream>>>(adj, ea, w_edge, xw_sw, out);
}